// Round 6
// baseline (489.664 us; speedup 1.0000x reference)
//
#include <hip/hip_runtime.h>

#define EPW 64       // edges per tile (one act tile per 2-wave block)
#define NTH 128      // 2 waves per block, nt-split
#define STRIDE 168   // padded feature stride in bf16 (336 B/row; 84%32=20 -> b128/b64 2-way max = free)

using f32x4 = __attribute__((ext_vector_type(4))) float;
using bf8   = __attribute__((ext_vector_type(8))) short;

__device__ __forceinline__ ushort f2bf(float f) {
    union { float f; unsigned u; } c{f};
    unsigned u = c.u;
    return (ushort)((u + 0x7fffu + ((u >> 16) & 1u)) >> 16);   // RTNE
}

__device__ __forceinline__ unsigned cvt_pk_bf16(float lo, float hi) {
    unsigned r;
    asm("v_cvt_pk_bf16_f32 %0, %1, %2" : "=v"(r) : "v"(lo), "v"(hi));
    return r;
}

// ---------------- weight repack: f32 [K][N] -> bf16 A-fragment lines ----------------
// A-frag (mfma_f32_16x16x32_bf16): lane l holds A[m=l&15][k=(l>>4)*8+j], j=0..7
// frag[((nt*KS+ks)*64+l)*8+j]; m = nt*16+(l&15); k = ks*32+(l>>4)*8+j
__global__ void repack_kernel(const float* __restrict__ Wstart,
                              const float* __restrict__ Wh0,
                              const float* __restrict__ Wh1,
                              const float* __restrict__ Wh2,
                              ushort* __restrict__ frag) {
    int i = blockIdx.x * blockDim.x + threadIdx.x;
    if (i < 4608) {                       // start: 9 nt * 1 ks * 64 * 8
        int j = i & 7, l = (i >> 3) & 63, nt = i >> 9;
        int k = ((l >> 4) << 3) + j;
        int n = nt * 16 + (l & 15);
        frag[i] = f2bf(Wstart[k * 144 + n]);
    } else if (i < 73728) {               // hidden: 3 * (9 nt * 5 ks * 64 * 8)
        int r = i - 4608;
        int h = r / 23040; r %= 23040;
        const float* W = (h == 0) ? Wh0 : ((h == 1) ? Wh1 : Wh2);
        int j = r & 7, l = (r >> 3) & 63, rem = r >> 9;
        int ks = rem % 5, nt = rem / 5;
        int k = ks * 32 + ((l >> 4) << 3) + j;
        int n = nt * 16 + (l & 15);
        float v = (k < 144) ? W[k * 144 + n] : 0.0f;
        frag[i] = f2bf(v);
    }
}

// ---- compute a compile-time nt range [NTB,NTE) for this wave; NO barrier inside ----
// C layout: col (l&15)=edge-in-16, row ((l>>4)*4+r)=out-feature [HW-verified].
template<int KS, int NTB, int NTE, bool FINAL>
__device__ __forceinline__ void compute_nts(const ushort* __restrict__ wfrag,
                                            const float* __restrict__ bias,
                                            ushort (*act)[STRIDE],
                                            const float* __restrict__ W_end,
                                            const bf8 (*xf)[KS],
                                            float* part, int lane) {
    const int grp = lane >> 4, er = lane & 15;
    #pragma unroll
    for (int nt = NTB; nt < NTE; nt++) {
        bf8 wf5[KS];
        #pragma unroll
        for (int k = 0; k < KS; k++)
            wf5[k] = *(const bf8*)&wfrag[(((nt * KS + k) << 6) + lane) << 3];
        f32x4 bv;
        {
            float4 b4 = *(const float4*)&bias[nt * 16 + grp * 4];
            bv[0] = b4.x; bv[1] = b4.y; bv[2] = b4.z; bv[3] = b4.w;
        }
        f32x4 acc[4] = {bv, bv, bv, bv};
        #pragma unroll
        for (int k = 0; k < KS; k++)
            #pragma unroll
            for (int t = 0; t < 4; t++)
                acc[t] = __builtin_amdgcn_mfma_f32_16x16x32_bf16(wf5[k], xf[t][k], acc[t], 0, 0, 0);

        if constexpr (FINAL) {
            float4 wv = *(const float4*)&W_end[nt * 16 + grp * 4];
            #pragma unroll
            for (int t = 0; t < 4; t++)
                part[t] += fmaxf(acc[t][0], 0.f) * wv.x + fmaxf(acc[t][1], 0.f) * wv.y
                         + fmaxf(acc[t][2], 0.f) * wv.z + fmaxf(acc[t][3], 0.f) * wv.w;
        } else {
            #pragma unroll
            for (int t = 0; t < 4; t++) {
                uint2 o;
                o.x = cvt_pk_bf16(fmaxf(acc[t][0], 0.f), fmaxf(acc[t][1], 0.f));
                o.y = cvt_pk_bf16(fmaxf(acc[t][2], 0.f), fmaxf(acc[t][3], 0.f));
                *(uint2*)&act[t * 16 + er][nt * 16 + grp * 4] = o;
            }
        }
    }
}

// ---- one fused layer: both waves read full xf; barrier; nt-disjoint compute/write; barrier ----
template<int KS, bool FINAL>
__device__ __forceinline__ void layer_w(const ushort* __restrict__ wfrag,
                                        const float* __restrict__ bias,
                                        ushort (*act)[STRIDE],
                                        const float* __restrict__ W_end,
                                        float* part, int wave, int lane) {
    const int grp = lane >> 4, er = lane & 15;
    bf8 xf[4][KS];
    #pragma unroll
    for (int t = 0; t < 4; t++)
        #pragma unroll
        for (int k = 0; k < KS; k++)
            xf[t][k] = *(const bf8*)&act[t * 16 + er][k * 32 + grp * 8];
    __syncthreads();   // all xf reads (both waves) complete before in-place writes

    if (wave == 0)
        compute_nts<KS, 0, 5, FINAL>(wfrag, bias, act, W_end, xf, part, lane);
    else
        compute_nts<KS, 5, 9, FINAL>(wfrag, bias, act, W_end, xf, part, lane);
    __syncthreads();   // writes visible before next layer's reads
}

__global__ __launch_bounds__(NTH, 4)
void mlp_kernel(const float* __restrict__ score,
                const int* __restrict__ label_idx,
                const float* __restrict__ b_start,
                const float* __restrict__ b_h0,
                const float* __restrict__ b_h1,
                const float* __restrict__ b_h2,
                const float* __restrict__ W_end,
                const float* __restrict__ b_end,
                const ushort* __restrict__ frag,
                float* __restrict__ out) {
    __shared__ ushort act[EPW][STRIDE];
    __shared__ float pdot[2 * EPW];
    const int tid = threadIdx.x;
    const int lane = tid & 63;
    const int wave = tid >> 6;
    const long gid = blockIdx.x;   // one 64-edge tile per block

    // zero K-pad cols 144..159 (layers never write cols >= 144)
    {
        uint4 z = {0u, 0u, 0u, 0u};
        *(uint4*)&act[tid >> 1][144 + ((tid & 1) << 3)] = z;
    }

    // gather: 64 edges x 32 idx = 512 int4 loads split across 128 threads
    const int4* lidx4 = (const int4*)label_idx + gid * 512;
    #pragma unroll
    for (int q = 0; q < 4; q++) {
        int p = q * 128 + tid;
        int4 v = lidx4[p];
        float f0 = score[v.x], f1 = score[v.y], f2 = score[v.z], f3 = score[v.w];
        uint2 o;
        o.x = cvt_pk_bf16(f0, f1);
        o.y = cvt_pk_bf16(f2, f3);
        *(uint2*)&act[p >> 3][(p & 7) << 2] = o;
    }
    __syncthreads();

    float part[4] = {0.f, 0.f, 0.f, 0.f};
    layer_w<1, false>(frag,                 b_start, act, nullptr, part, wave, lane);
    layer_w<5, false>(frag + 4608,          b_h0,    act, nullptr, part, wave, lane);
    layer_w<5, false>(frag + 4608 + 23040,  b_h1,    act, nullptr, part, wave, lane);
    // FINAL layer: compute partial dots, write pdot inside, trailing barrier in layer_w
    {
        const int grp = lane >> 4, er = lane & 15;
        bf8 xf[4][5];
        #pragma unroll
        for (int t = 0; t < 4; t++)
            #pragma unroll
            for (int k = 0; k < 5; k++)
                xf[t][k] = *(const bf8*)&act[t * 16 + er][k * 32 + grp * 8];
        __syncthreads();
        if (wave == 0)
            compute_nts<5, 0, 5, true>(frag + 4608 + 46080, b_h2, act, W_end, xf, part, lane);
        else
            compute_nts<5, 5, 9, true>(frag + 4608 + 46080, b_h2, act, W_end, xf, part, lane);
        // reduce each wave's partial dot across its 4 lane-groups
        #pragma unroll
        for (int t = 0; t < 4; t++) {
            part[t] += __shfl_xor(part[t], 16, 64);
            part[t] += __shfl_xor(part[t], 32, 64);
        }
        if (lane < 16) {
            #pragma unroll
            for (int t = 0; t < 4; t++)
                pdot[wave * EPW + t * 16 + lane] = part[t];
        }
        __syncthreads();
    }
    if (tid < EPW)
        out[gid * EPW + tid] = b_end[0] + pdot[tid] + pdot[EPW + tid];
}

extern "C" void kernel_launch(void* const* d_in, const int* in_sizes, int n_in,
                              void* d_out, int out_size, void* d_ws, size_t ws_size,
                              hipStream_t stream) {
    const float* score   = (const float*)d_in[0];
    const int*   lidx    = (const int*)  d_in[1];
    const float* W_start = (const float*)d_in[2];
    const float* b_start = (const float*)d_in[3];
    const float* W_h0    = (const float*)d_in[4];
    const float* b_h0    = (const float*)d_in[5];
    const float* W_h1    = (const float*)d_in[6];
    const float* b_h1    = (const float*)d_in[7];
    const float* W_h2    = (const float*)d_in[8];
    const float* b_h2    = (const float*)d_in[9];
    const float* W_end   = (const float*)d_in[10];
    const float* b_end   = (const float*)d_in[11];
    float* out = (float*)d_out;

    ushort* frag = (ushort*)d_ws;   // 73728 bf16 = 147456 B of repacked weights

    const int n_edges = in_sizes[1] / 32;   // label_idx is [E][32]; in_sizes is FLAT count

    repack_kernel<<<288, 256, 0, stream>>>(W_start, W_h0, W_h1, W_h2, frag);

    mlp_kernel<<<n_edges / EPW, NTH, 0, stream>>>(score, lidx, b_start, b_h0, b_h1, b_h2,
                                                  W_end, b_end, frag, out);
}

// Round 7
// 270.215 us; speedup vs baseline: 1.8121x; 1.8121x over previous
//
#include <hip/hip_runtime.h>

#define EPW 64       // edges per tile (one act tile per 2-wave block)
#define NTH 128      // 2 waves per block, nt-split (wave0: nt 0-4, wave1: nt 5-8)
#define STRIDE 168   // bf16 feature stride (336 B/row; 84 dw % 32 -> b128 reads are 2-way max = free)

using f32x4 = __attribute__((ext_vector_type(4))) float;
using bf8   = __attribute__((ext_vector_type(8))) short;

__device__ __forceinline__ ushort f2bf(float f) {
    union { float f; unsigned u; } c{f};
    unsigned u = c.u;
    return (ushort)((u + 0x7fffu + ((u >> 16) & 1u)) >> 16);   // RTNE
}

__device__ __forceinline__ unsigned cvt_pk_bf16(float lo, float hi) {
    unsigned r;
    asm("v_cvt_pk_bf16_f32 %0, %1, %2" : "=v"(r) : "v"(lo), "v"(hi));
    return r;
}

// ---------------- weight repack: f32 [K][N] -> bf16 A-fragment lines ----------------
// A-frag (mfma_f32_16x16x32_bf16): lane l holds A[m=l&15][k=(l>>4)*8+j], j=0..7
// frag[((nt*KS+ks)*64+l)*8+j]; m = nt*16+(l&15); k = ks*32+(l>>4)*8+j
__global__ void repack_kernel(const float* __restrict__ Wstart,
                              const float* __restrict__ Wh0,
                              const float* __restrict__ Wh1,
                              const float* __restrict__ Wh2,
                              ushort* __restrict__ frag) {
    int i = blockIdx.x * blockDim.x + threadIdx.x;
    if (i < 4608) {                       // start: 9 nt * 1 ks * 64 * 8
        int j = i & 7, l = (i >> 3) & 63, nt = i >> 9;
        int k = ((l >> 4) << 3) + j;
        int n = nt * 16 + (l & 15);
        frag[i] = f2bf(Wstart[k * 144 + n]);
    } else if (i < 73728) {               // hidden: 3 * (9 nt * 5 ks * 64 * 8)
        int r = i - 4608;
        int h = r / 23040; r %= 23040;
        const float* W = (h == 0) ? Wh0 : ((h == 1) ? Wh1 : Wh2);
        int j = r & 7, l = (r >> 3) & 63, rem = r >> 9;
        int ks = rem % 5, nt = rem / 5;
        int k = ks * 32 + ((l >> 4) << 3) + j;
        int n = nt * 16 + (l & 15);
        float v = (k < 144) ? W[k * 144 + n] : 0.0f;
        frag[i] = f2bf(v);
    }
}

// ---- one fused layer for a compile-time nt range; xf is a plain local (register) array ----
// in-place safety: BOTH waves read full xf before barrier1; nt-disjoint writes after.
// C layout: col (l&15)=edge-in-16, row ((l>>4)*4+r)=out-feature [HW-verified].
template<int KS, int NTB, int NTE, bool FINAL>
__device__ __forceinline__ void layer_impl(const ushort* __restrict__ wfrag,
                                           const float* __restrict__ bias,
                                           ushort (*act)[STRIDE],
                                           const float* __restrict__ W_end,
                                           float* part, int lane) {
    const int grp = lane >> 4, er = lane & 15;
    bf8 xf[4][KS];
    #pragma unroll
    for (int t = 0; t < 4; t++)
        #pragma unroll
        for (int k = 0; k < KS; k++)
            xf[t][k] = *(const bf8*)&act[t * 16 + er][k * 32 + grp * 8];
    __syncthreads();   // all xf reads (both waves) complete before in-place writes

    #pragma unroll
    for (int nt = NTB; nt < NTE; nt++) {
        bf8 wf[KS];
        #pragma unroll
        for (int k = 0; k < KS; k++)
            wf[k] = *(const bf8*)&wfrag[(((nt * KS + k) << 6) + lane) << 3];
        f32x4 bv;
        {
            float4 b4 = *(const float4*)&bias[nt * 16 + grp * 4];
            bv[0] = b4.x; bv[1] = b4.y; bv[2] = b4.z; bv[3] = b4.w;
        }
        f32x4 acc[4] = {bv, bv, bv, bv};
        #pragma unroll
        for (int k = 0; k < KS; k++)
            #pragma unroll
            for (int t = 0; t < 4; t++)
                acc[t] = __builtin_amdgcn_mfma_f32_16x16x32_bf16(wf[k], xf[t][k], acc[t], 0, 0, 0);

        if constexpr (FINAL) {
            float4 wv = *(const float4*)&W_end[nt * 16 + grp * 4];
            #pragma unroll
            for (int t = 0; t < 4; t++)
                part[t] += fmaxf(acc[t][0], 0.f) * wv.x + fmaxf(acc[t][1], 0.f) * wv.y
                         + fmaxf(acc[t][2], 0.f) * wv.z + fmaxf(acc[t][3], 0.f) * wv.w;
        } else {
            #pragma unroll
            for (int t = 0; t < 4; t++) {
                uint2 o;
                o.x = cvt_pk_bf16(fmaxf(acc[t][0], 0.f), fmaxf(acc[t][1], 0.f));
                o.y = cvt_pk_bf16(fmaxf(acc[t][2], 0.f), fmaxf(acc[t][3], 0.f));
                *(uint2*)&act[t * 16 + er][nt * 16 + grp * 4] = o;
            }
        }
    }
    __syncthreads();   // writes visible before next layer's xf reads
}

// ---- whole 4-layer chain for one wave's compile-time nt range ----
template<int NTB, int NTE>
__device__ __forceinline__ void chain(const ushort* __restrict__ frag,
                                      const float* __restrict__ b_start,
                                      const float* __restrict__ b_h0,
                                      const float* __restrict__ b_h1,
                                      const float* __restrict__ b_h2,
                                      const float* __restrict__ W_end,
                                      ushort (*act)[STRIDE],
                                      float* part, int lane) {
    layer_impl<1, NTB, NTE, false>(frag,                 b_start, act, nullptr, part, lane);
    layer_impl<5, NTB, NTE, false>(frag + 4608,          b_h0,    act, nullptr, part, lane);
    layer_impl<5, NTB, NTE, false>(frag + 4608 + 23040,  b_h1,    act, nullptr, part, lane);
    layer_impl<5, NTB, NTE, true >(frag + 4608 + 46080,  b_h2,    act, W_end,   part, lane);
}

__global__ __launch_bounds__(NTH, 3)
void mlp_kernel(const float* __restrict__ score,
                const int* __restrict__ label_idx,
                const float* __restrict__ b_start,
                const float* __restrict__ b_h0,
                const float* __restrict__ b_h1,
                const float* __restrict__ b_h2,
                const float* __restrict__ W_end,
                const float* __restrict__ b_end,
                const ushort* __restrict__ frag,
                float* __restrict__ out) {
    __shared__ ushort act[EPW][STRIDE];
    __shared__ float pdot[2 * EPW];
    const int tid = threadIdx.x;
    const int lane = tid & 63;
    const int wave = tid >> 6;
    const long gid = blockIdx.x;   // one 64-edge tile per block

    // zero K-pad cols 144..159 (layers never write cols >= 144)
    {
        uint4 z = {0u, 0u, 0u, 0u};
        *(uint4*)&act[tid >> 1][144 + ((tid & 1) << 3)] = z;
    }

    // gather: 64 edges x 32 idx = 512 int4 loads split across 128 threads
    const int4* lidx4 = (const int4*)label_idx + gid * 512;
    #pragma unroll
    for (int q = 0; q < 4; q++) {
        int p = q * 128 + tid;
        int4 v = lidx4[p];
        float f0 = score[v.x], f1 = score[v.y], f2 = score[v.z], f3 = score[v.w];
        uint2 o;
        o.x = cvt_pk_bf16(f0, f1);
        o.y = cvt_pk_bf16(f2, f3);
        *(uint2*)&act[p >> 3][(p & 7) << 2] = o;
    }
    __syncthreads();

    // wave-specialized chain; barriers inside are wave-uniform (s_barrier counts arrivals)
    float part[4] = {0.f, 0.f, 0.f, 0.f};
    if (wave == 0)
        chain<0, 5>(frag, b_start, b_h0, b_h1, b_h2, W_end, act, part, lane);
    else
        chain<5, 9>(frag, b_start, b_h0, b_h1, b_h2, W_end, act, part, lane);

    // reduce each wave's W_end partial dot across its 4 lane-groups
    #pragma unroll
    for (int t = 0; t < 4; t++) {
        part[t] += __shfl_xor(part[t], 16, 64);
        part[t] += __shfl_xor(part[t], 32, 64);
    }
    if (lane < 16) {
        #pragma unroll
        for (int t = 0; t < 4; t++)
            pdot[wave * EPW + t * 16 + lane] = part[t];
    }
    __syncthreads();
    if (tid < EPW)
        out[gid * EPW + tid] = b_end[0] + pdot[tid] + pdot[EPW + tid];
}

extern "C" void kernel_launch(void* const* d_in, const int* in_sizes, int n_in,
                              void* d_out, int out_size, void* d_ws, size_t ws_size,
                              hipStream_t stream) {
    const float* score   = (const float*)d_in[0];
    const int*   lidx    = (const int*)  d_in[1];
    const float* W_start = (const float*)d_in[2];
    const float* b_start = (const float*)d_in[3];
    const float* W_h0    = (const float*)d_in[4];
    const float* b_h0    = (const float*)d_in[5];
    const float* W_h1    = (const float*)d_in[6];
    const float* b_h1    = (const float*)d_in[7];
    const float* W_h2    = (const float*)d_in[8];
    const float* b_h2    = (const float*)d_in[9];
    const float* W_end   = (const float*)d_in[10];
    const float* b_end   = (const float*)d_in[11];
    float* out = (float*)d_out;

    ushort* frag = (ushort*)d_ws;   // 73728 bf16 = 147456 B of repacked weights

    const int n_edges = in_sizes[1] / 32;   // label_idx is [E][32]; in_sizes is FLAT count

    repack_kernel<<<288, 256, 0, stream>>>(W_start, W_h0, W_h1, W_h2, frag);

    mlp_kernel<<<n_edges / EPW, NTH, 0, stream>>>(score, lidx, b_start, b_h0, b_h1, b_h2,
                                                  W_end, b_end, frag, out);
}

// Round 8
// 258.910 us; speedup vs baseline: 1.8913x; 1.0437x over previous
//
#include <hip/hip_runtime.h>

#define EPW 64       // edges per tile (one act tile per 2-wave block)
#define NTH 128      // 2 waves per block, nt-split (wave0: nt 0-4, wave1: nt 5-8)
#define STRIDE 168   // bf16 feature stride (336 B/row; b128 reads 2-way bank alias max = free)

using f32x4 = __attribute__((ext_vector_type(4))) float;
using bf8   = __attribute__((ext_vector_type(8))) short;

__device__ __forceinline__ ushort f2bf(float f) {
    union { float f; unsigned u; } c{f};
    unsigned u = c.u;
    return (ushort)((u + 0x7fffu + ((u >> 16) & 1u)) >> 16);   // RTNE
}

__device__ __forceinline__ unsigned cvt_pk_bf16(float lo, float hi) {
    unsigned r;
    asm("v_cvt_pk_bf16_f32 %0, %1, %2" : "=v"(r) : "v"(lo), "v"(hi));
    return r;
}

// ---------------- weight repack: f32 [K][N] -> bf16 A-fragment lines ----------------
// A-frag (mfma_f32_16x16x32_bf16): lane l holds A[m=l&15][k=(l>>4)*8+j], j=0..7
// frag[((nt*KS+ks)*64+l)*8+j]; m = nt*16+(l&15); k = ks*32+(l>>4)*8+j
__global__ void repack_kernel(const float* __restrict__ Wstart,
                              const float* __restrict__ Wh0,
                              const float* __restrict__ Wh1,
                              const float* __restrict__ Wh2,
                              ushort* __restrict__ frag) {
    int i = blockIdx.x * blockDim.x + threadIdx.x;
    if (i < 4608) {                       // start: 9 nt * 1 ks * 64 * 8
        int j = i & 7, l = (i >> 3) & 63, nt = i >> 9;
        int k = ((l >> 4) << 3) + j;
        int n = nt * 16 + (l & 15);
        frag[i] = f2bf(Wstart[k * 144 + n]);
    } else if (i < 73728) {               // hidden: 3 * (9 nt * 5 ks * 64 * 8)
        int r = i - 4608;
        int h = r / 23040; r %= 23040;
        const float* W = (h == 0) ? Wh0 : ((h == 1) ? Wh1 : Wh2);
        int j = r & 7, l = (r >> 3) & 63, rem = r >> 9;
        int ks = rem % 5, nt = rem / 5;
        int k = ks * 32 + ((l >> 4) << 3) + j;
        int n = nt * 16 + (l & 15);
        float v = (k < 144) ? W[k * 144 + n] : 0.0f;
        frag[i] = f2bf(v);
    }
}

// ---- one fused layer for a compile-time nt range; xf is a plain local (register) array ----
// in-place safety: BOTH waves read full xf before barrier1; nt-disjoint writes after.
// C layout: col (l&15)=edge-in-16, row ((l>>4)*4+r)=out-feature [HW-verified].
template<int KS, int NTB, int NTE, bool FINAL>
__device__ __forceinline__ void layer_impl(const ushort* __restrict__ wfrag,
                                           const float* __restrict__ bias,
                                           ushort (*act)[STRIDE],
                                           const float* __restrict__ W_end,
                                           float* part, int lane) {
    const int grp = lane >> 4, er = lane & 15;
    bf8 xf[4][KS];
    #pragma unroll
    for (int t = 0; t < 4; t++)
        #pragma unroll
        for (int k = 0; k < KS; k++)
            xf[t][k] = *(const bf8*)&act[t * 16 + er][k * 32 + grp * 8];
    __syncthreads();   // all xf reads (both waves) complete before in-place writes

    #pragma unroll
    for (int nt = NTB; nt < NTE; nt++) {
        bf8 wf[KS];
        #pragma unroll
        for (int k = 0; k < KS; k++)
            wf[k] = *(const bf8*)&wfrag[(((nt * KS + k) << 6) + lane) << 3];
        f32x4 bv;
        {
            float4 b4 = *(const float4*)&bias[nt * 16 + grp * 4];
            bv[0] = b4.x; bv[1] = b4.y; bv[2] = b4.z; bv[3] = b4.w;
        }
        f32x4 acc[4] = {bv, bv, bv, bv};
        #pragma unroll
        for (int k = 0; k < KS; k++)
            #pragma unroll
            for (int t = 0; t < 4; t++)
                acc[t] = __builtin_amdgcn_mfma_f32_16x16x32_bf16(wf[k], xf[t][k], acc[t], 0, 0, 0);

        if constexpr (FINAL) {
            float4 wv = *(const float4*)&W_end[nt * 16 + grp * 4];
            #pragma unroll
            for (int t = 0; t < 4; t++)
                part[t] += fmaxf(acc[t][0], 0.f) * wv.x + fmaxf(acc[t][1], 0.f) * wv.y
                         + fmaxf(acc[t][2], 0.f) * wv.z + fmaxf(acc[t][3], 0.f) * wv.w;
        } else {
            #pragma unroll
            for (int t = 0; t < 4; t++) {
                uint2 o;
                o.x = cvt_pk_bf16(fmaxf(acc[t][0], 0.f), fmaxf(acc[t][1], 0.f));
                o.y = cvt_pk_bf16(fmaxf(acc[t][2], 0.f), fmaxf(acc[t][3], 0.f));
                *(uint2*)&act[t * 16 + er][nt * 16 + grp * 4] = o;
            }
        }
    }
    __syncthreads();   // writes visible before next layer's xf reads
}

// ---- whole 4-layer chain for one wave's compile-time nt range ----
template<int NTB, int NTE>
__device__ __forceinline__ void chain(const ushort* __restrict__ frag,
                                      const float* __restrict__ b_start,
                                      const float* __restrict__ b_h0,
                                      const float* __restrict__ b_h1,
                                      const float* __restrict__ b_h2,
                                      const float* __restrict__ W_end,
                                      ushort (*act)[STRIDE],
                                      float* part, int lane) {
    layer_impl<1, NTB, NTE, false>(frag,                 b_start, act, nullptr, part, lane);
    layer_impl<5, NTB, NTE, false>(frag + 4608,          b_h0,    act, nullptr, part, lane);
    layer_impl<5, NTB, NTE, false>(frag + 4608 + 23040,  b_h1,    act, nullptr, part, lane);
    layer_impl<5, NTB, NTE, true >(frag + 4608 + 46080,  b_h2,    act, W_end,   part, lane);
}

__global__ __launch_bounds__(NTH, 2)
void mlp_kernel(const float* __restrict__ score,
                const int* __restrict__ label_idx,
                const float* __restrict__ b_start,
                const float* __restrict__ b_h0,
                const float* __restrict__ b_h1,
                const float* __restrict__ b_h2,
                const float* __restrict__ W_end,
                const float* __restrict__ b_end,
                const ushort* __restrict__ frag,
                float* __restrict__ out) {
    __shared__ ushort act[EPW][STRIDE];
    __shared__ float pdot[2 * EPW];
    const int tid = threadIdx.x;
    const int lane = tid & 63;
    const int wave = tid >> 6;
    const long gid = blockIdx.x;   // one 64-edge tile per block

    // zero K-pad cols 144..159 (layers never write cols >= 144)
    {
        uint4 z = {0u, 0u, 0u, 0u};
        *(uint4*)&act[tid >> 1][144 + ((tid & 1) << 3)] = z;
    }

    // gather: 64 edges x 32 idx = 512 int4 loads split across 128 threads
    const int4* lidx4 = (const int4*)label_idx + gid * 512;
    #pragma unroll
    for (int q = 0; q < 4; q++) {
        int p = q * 128 + tid;
        int4 v = lidx4[p];
        float f0 = score[v.x], f1 = score[v.y], f2 = score[v.z], f3 = score[v.w];
        uint2 o;
        o.x = cvt_pk_bf16(f0, f1);
        o.y = cvt_pk_bf16(f2, f3);
        *(uint2*)&act[p >> 3][(p & 7) << 2] = o;
    }
    __syncthreads();

    // wave-specialized chain; barriers inside are wave-uniform per wave (s_barrier counts arrivals)
    float part[4] = {0.f, 0.f, 0.f, 0.f};
    if (wave == 0)
        chain<0, 5>(frag, b_start, b_h0, b_h1, b_h2, W_end, act, part, lane);
    else
        chain<5, 9>(frag, b_start, b_h0, b_h1, b_h2, W_end, act, part, lane);

    // reduce each wave's W_end partial dot across its 4 lane-groups
    #pragma unroll
    for (int t = 0; t < 4; t++) {
        part[t] += __shfl_xor(part[t], 16, 64);
        part[t] += __shfl_xor(part[t], 32, 64);
    }
    if (lane < 16) {
        #pragma unroll
        for (int t = 0; t < 4; t++)
            pdot[wave * EPW + t * 16 + lane] = part[t];
    }
    __syncthreads();
    if (tid < EPW)
        out[gid * EPW + tid] = b_end[0] + pdot[tid] + pdot[EPW + tid];
}

extern "C" void kernel_launch(void* const* d_in, const int* in_sizes, int n_in,
                              void* d_out, int out_size, void* d_ws, size_t ws_size,
                              hipStream_t stream) {
    const float* score   = (const float*)d_in[0];
    const int*   lidx    = (const int*)  d_in[1];
    const float* W_start = (const float*)d_in[2];
    const float* b_start = (const float*)d_in[3];
    const float* W_h0    = (const float*)d_in[4];
    const float* b_h0    = (const float*)d_in[5];
    const float* W_h1    = (const float*)d_in[6];
    const float* b_h1    = (const float*)d_in[7];
    const float* W_h2    = (const float*)d_in[8];
    const float* b_h2    = (const float*)d_in[9];
    const float* W_end   = (const float*)d_in[10];
    const float* b_end   = (const float*)d_in[11];
    float* out = (float*)d_out;

    ushort* frag = (ushort*)d_ws;   // 73728 bf16 = 147456 B of repacked weights

    const int n_edges = in_sizes[1] / 32;   // label_idx is [E][32]; in_sizes is FLAT count

    repack_kernel<<<288, 256, 0, stream>>>(W_start, W_h0, W_h1, W_h2, frag);

    mlp_kernel<<<n_edges / EPW, NTH, 0, stream>>>(score, lidx, b_start, b_h0, b_h1, b_h2,
                                                  W_end, b_end, frag, out);
}